// Round 5
// baseline (253.453 us; speedup 1.0000x reference)
//
#include <hip/hip_runtime.h>
#include <hip/hip_bf16.h>
#include <stdint.h>
#include <stddef.h>

// E=8, B=16, T=512, DIN=256, D=256; M = B*T = 8192 rows per ensemble member.
// Stage1: u = x @ W_in[m], v=tanh(u0), f=sig(u1)*(1-rs)  -> scan1 -> v4
// Stage2: u = v4 @ W_mid[m], gates f,i,o,z               -> scan2 -> g = h*o
// Stage3: out = g @ W_out + b_out
//
// r5: persistent B-in-register GEMM (r4) +
//  (a) exact vmcnt accounting incl. epilogue stores (stores pollute the
//      in-order vmcnt queue; wait 12+NS while stores are younger than the
//      needed chunk, 12 otherwise)
//  (b) gate-interleaved Wt columns (n' = d*NG+g): epilogue fuses per-(m,d)
//      gate math; stage1 writes packed (b,f); stage2 writes (f,b)+o
//      [3 slabs instead of 4 -> -64MB HBM]

typedef __bf16 bf16x8 __attribute__((ext_vector_type(8)));
typedef __bf16 bf16x4 __attribute__((ext_vector_type(4)));
typedef __bf16 bf16x2 __attribute__((ext_vector_type(2)));
typedef float  f32x4  __attribute__((ext_vector_type(4)));
typedef unsigned int u32x2 __attribute__((ext_vector_type(2)));

#define E_ 8
#define M_ 8192
#define K_ 256

__device__ __forceinline__ float sigm_f(float x) { return 1.0f / (1.0f + __expf(-x)); }
__device__ __forceinline__ float tanh_f(float x) { return 1.0f - 2.0f / (1.0f + __expf(2.0f * x)); }

__device__ __forceinline__ void g2lds16(const void* g, void* l) {
    __builtin_amdgcn_global_load_lds((const __attribute__((address_space(1))) void*)g,
                                     (__attribute__((address_space(3))) void*)l, 16, 0, 0);
}

// ---------------- convert x to bf16 ----------------
__global__ __launch_bounds__(256) void convx_k(const float* __restrict__ x, __bf16* __restrict__ xb) {
    int i = blockIdx.x * 256 + threadIdx.x;
    float4 v = ((const float4*)x)[i];
    bf16x4 o;
    o[0] = (__bf16)v.x; o[1] = (__bf16)v.y; o[2] = (__bf16)v.z; o[3] = (__bf16)v.w;
    ((bf16x4*)xb)[i] = o;
}

// ---------------- rs -> tile-layout (1-rs) table ----------------
__global__ __launch_bounds__(256) void rsprep_k(const float* __restrict__ rs, float* __restrict__ rsp) {
    int idx = blockIdx.x * 256 + threadIdx.x;      // 0..8191
    int mt = idx >> 7, rem = idx & 127;
    int half = rem >> 6, r15 = (rem >> 2) & 15, i = rem & 3;
    rsp[idx] = 1.0f - rs[mt * 128 + half * 64 + i * 16 + r15];
}

// ---------------- transpose+convert weights ----------------
// src [GE][K][D] f32 -> dst [E][NG*256][K] bf16; row' = ilv ? d*NG+g : g*256+d
__global__ __launch_bounds__(256) void transw_k(const float* __restrict__ src, __bf16* __restrict__ dst,
                                                int NG, int ilv) {
    int ge = blockIdx.z;
    int g = ge >> 3, e = ge & 7;
    int k0 = blockIdx.x * 64, d0 = blockIdx.y * 64;
    __shared__ float tile[64][65];
    int t = threadIdx.x;
#pragma unroll
    for (int j = 0; j < 16; ++j) {
        int lin = j * 256 + t;
        int r = lin >> 6, c = lin & 63;
        tile[r][c] = src[((size_t)(ge * 256 + k0 + r)) * 256 + d0 + c];
    }
    __syncthreads();
#pragma unroll
    for (int j = 0; j < 16; ++j) {
        int lin = j * 256 + t;
        int r = lin >> 6, c = lin & 63;     // r = d offset, c = k offset
        int d = d0 + r;
        int row = ilv ? (d * NG + g) : (g * 256 + d);
        dst[((size_t)(e * NG * 256 + row)) * K_ + k0 + c] = (__bf16)tile[c][r];
    }
}

// ---------------- persistent GEMM, B-in-registers, gate-interleaved ----------------
// MODE 0: NG=2 ilv (q: v(d0),f(d0),v(d1),f(d1)) -> packed {b,f} pairs, slab [E][M][512]
// MODE 1: NG=4 ilv (q: f,i,o,z of one d) -> FB slab [E][M][256]x(f,b) + O slab [E][M][256]
// MODE 2: NG=1 linear+bias -> f32 d_out
template <int MODE, int NG, int NMT>
__global__ __launch_bounds__(256, 2) void gemm_k(const __bf16* __restrict__ A,
                                                 const __bf16* __restrict__ Wt,
                                                 const float* __restrict__ bias,
                                                 const float* __restrict__ rsp,
                                                 __bf16* __restrict__ gout,
                                                 __bf16* __restrict__ gout2,
                                                 float* __restrict__ fout) {
    constexpr int NT = NG * 2;                 // n-panels of 128
    constexpr int NC = NMT * 8;                // k32-chunks streamed per block
    const int tid = threadIdx.x;
    const int bid = blockIdx.x;                // 512 blocks
    const int e = bid & 7;
    const int r = bid >> 3;                    // 0..63
    const int nt = r % NT;
    const int ms = r / NT;
    const int mt0 = ms * NMT;
    const int lane = tid & 63, wid = tid >> 6;
    const int wr = wid >> 1, wc = wid & 1;     // 2x2 wave grid over 128x128 tile

    __shared__ __align__(16) __bf16 As[8][4096];   // 8 bufs x (128 rows x 32 k) = 64 KB

    // ---- B panel into registers ----
    const size_t Bbase = ((size_t)e * (NG * 256) + nt * 128) * K_;
    bf16x8 Breg[4][8];
    {
        const __bf16* bp = Wt + Bbase + (size_t)(wc * 64 + (lane & 15)) * K_ + (lane >> 4) * 8;
#pragma unroll
        for (int j = 0; j < 4; ++j)
#pragma unroll
            for (int kc = 0; kc < 8; ++kc)
                Breg[j][kc] = *(const bf16x8*)(bp + j * 16 * K_ + kc * 32);
    }
    // ---- bias preload (per-q gather honoring interleave) ----
    f32x4 bias_v[4];
#pragma unroll
    for (int j = 0; j < 4; ++j) {
#pragma unroll
        for (int q = 0; q < 4; ++q) {
            int n = nt * 128 + wc * 64 + j * 16 + ((lane >> 4) << 2) + q;
            int g, d;
            if constexpr (MODE == 0)      { g = n & 1; d = n >> 1; }
            else if constexpr (MODE == 1) { g = n & 3; d = n >> 2; }
            else                          { g = 0;     d = n; }
            bias_v[j][q] = bias[(g * E_ + e) * 256 + d];
        }
    }

    // ---- per-thread staging source bases ----
    const size_t Ae = ((size_t)e * M_ + (size_t)mt0 * 128) * K_;
    const int P0 = tid, P1 = 256 + tid;
    const int r0 = P0 >> 2, g0 = (P0 & 3) ^ ((r0 >> 1) & 3);
    const int r1 = P1 >> 2, g1 = (P1 & 3) ^ ((r1 >> 1) & 3);
    const __bf16* sA0 = A + Ae + (size_t)r0 * K_ + g0 * 8;
    const __bf16* sA1 = A + Ae + (size_t)r1 * K_ + g1 * 8;
    __bf16* const ld0 = &As[0][0] + P0 * 8;
    __bf16* const ld1 = &As[0][0] + P1 * 8;

    auto stage = [&](int c) {
        int off = (c >> 3) * (128 * K_) + (c & 7) * 32;
        int lo = (c & 7) * 4096;
        g2lds16(sA0 + off, ld0 + lo);
        g2lds16(sA1 + off, ld1 + lo);
    };

    const __bf16* abase = &As[0][0]
        + (wr * 64 + (lane & 15)) * 32
        + (((lane >> 4) ^ (((lane & 15) >> 1) & 3)) * 8);

#pragma unroll
    for (int c = 0; c < 7; ++c) stage(c);

    f32x4 acc[4][4] = {};

    for (int t = 0; t < NMT; ++t) {
        f32x4 rsv;
        if (MODE != 2) rsv = *(const f32x4*)&rsp[(mt0 + t) * 128 + wr * 64 + (lane & 15) * 4];
#pragma unroll
        for (int s = 0; s < 8; ++s) {
            const int c = t * 8 + s;
            // exact vmcnt: ops younger than chunk c = 12 loads (+NS stores if
            // last epilogue's stores were issued after chunk c's stage)
            if (t == 0 || s == 7) {
                asm volatile("s_waitcnt vmcnt(12)" ::: "memory");
            } else {
                if constexpr (MODE == 1) asm volatile("s_waitcnt vmcnt(44)" ::: "memory");
                else                     asm volatile("s_waitcnt vmcnt(28)" ::: "memory");
            }
            __builtin_amdgcn_s_barrier();
            {
                int cn = c + 7; if (cn > NC - 1) cn = NC - 1;
                stage(cn);
            }
            bf16x8 af[4];
#pragma unroll
            for (int i = 0; i < 4; ++i)
                af[i] = *(const bf16x8*)(abase + s * 4096 + i * 512);
#pragma unroll
            for (int i = 0; i < 4; ++i)
#pragma unroll
                for (int j = 0; j < 4; ++j)
                    acc[i][j] = __builtin_amdgcn_mfma_f32_16x16x32_bf16(Breg[j][s], af[i], acc[i][j], 0, 0, 0);
        }

        // ---- epilogue for mt = mt0+t ----
        const int mlo = (mt0 + t) * 128 + wr * 64 + (lane & 15);
#pragma unroll
        for (int j = 0; j < 4; ++j) {
            const int n0 = nt * 128 + wc * 64 + j * 16 + ((lane >> 4) << 2);
#pragma unroll
            for (int i = 0; i < 4; ++i) {
                const int m = mlo + i * 16;
                float u0 = acc[i][j][0] + bias_v[j][0];
                float u1 = acc[i][j][1] + bias_v[j][1];
                float u2 = acc[i][j][2] + bias_v[j][2];
                float u3 = acc[i][j][3] + bias_v[j][3];
                if constexpr (MODE == 2) {
                    f32x4 o; o[0] = u0; o[1] = u1; o[2] = u2; o[3] = u3;
                    *(f32x4*)&fout[((size_t)e * M_ + m) * 256 + n0] = o;
                } else if constexpr (MODE == 0) {
                    // q: v(d0), f(d0), v(d1), f(d1)
                    float v0 = tanh_f(u0), f0 = sigm_f(u1) * rsv[i];
                    float v1 = tanh_f(u2), f1 = sigm_f(u3) * rsv[i];
                    bf16x4 pk;
                    pk[0] = (__bf16)((1.0f - f0) * v0); pk[1] = (__bf16)f0;
                    pk[2] = (__bf16)((1.0f - f1) * v1); pk[3] = (__bf16)f1;
                    *(u32x2*)&gout[((size_t)e * M_ + m) * 512 + n0] = __builtin_bit_cast(u32x2, pk);
                } else {
                    // q: f, i, o, z of one d
                    const int d = n0 >> 2;
                    float f = sigm_f(u0) * rsv[i];
                    float iv = sigm_f(u1);
                    float o = sigm_f(u2);
                    float z = tanh_f(u3);
                    float b = (1.0f - f) * (iv * z);
                    bf16x2 fb; fb[0] = (__bf16)f; fb[1] = (__bf16)b;
                    *(unsigned int*)&gout[(((size_t)e * M_ + m) * 256 + d) * 2] =
                        __builtin_bit_cast(unsigned int, fb);
                    gout2[((size_t)e * M_ + m) * 256 + d] = (__bf16)o;
                }
                acc[i][j] = f32x4{};
            }
        }
    }
}

// ---------------- scan 1: h = f*h + b, packed (b,f) slab [E][M][512] ----
__global__ __launch_bounds__(64) void scan1_k(const __bf16* __restrict__ BF,
                                              const float* __restrict__ hidden,
                                              __bf16* __restrict__ v4b, float* __restrict__ hidout) {
    int gid = blockIdx.x * 64 + threadIdx.x;    // 0..32767
    int n = gid >> 8, d = gid & 255;
    float h = hidden[n * 512 + d];
    const unsigned int* bf = (const unsigned int*)BF;
    size_t base = (size_t)n * 512 * 256 + (size_t)d;   // uint index: row stride 256
    size_t obase = (size_t)n * 512 * 256 + d;
#pragma unroll 1
    for (int tb = 0; tb < 512; tb += 16) {
        bf16x2 w[16];
#pragma unroll
        for (int u = 0; u < 16; ++u)
            w[u] = __builtin_bit_cast(bf16x2, bf[base + (size_t)(tb + u) * 256]);
#pragma unroll
        for (int u = 0; u < 16; ++u) {
            float b = (float)w[u][0], f = (float)w[u][1];
            h = __builtin_fmaf(f, h, b);
            v4b[obase + (size_t)(tb + u) * 256] = (__bf16)h;
        }
    }
    hidout[n * 512 + d] = h;
}

// ---------------- scan 2: h = f*h + b; out = h*o ----
__global__ __launch_bounds__(64) void scan2_k(const __bf16* __restrict__ FB, const __bf16* __restrict__ O,
                                              const float* __restrict__ hidden,
                                              __bf16* __restrict__ G, float* __restrict__ hidout) {
    int gid = blockIdx.x * 64 + threadIdx.x;
    int n = gid >> 8, d = gid & 255;
    float h = hidden[n * 512 + 256 + d];
    const unsigned int* fb = (const unsigned int*)FB;
    size_t base = (size_t)n * 512 * 256 + d;
#pragma unroll 1
    for (int tb = 0; tb < 512; tb += 16) {
        bf16x2 w[16];
        float ov[16];
#pragma unroll
        for (int u = 0; u < 16; ++u) {
            size_t idx = base + (size_t)(tb + u) * 256;
            w[u] = __builtin_bit_cast(bf16x2, fb[idx]);
            ov[u] = (float)O[idx];
        }
#pragma unroll
        for (int u = 0; u < 16; ++u) {
            float f = (float)w[u][0], b = (float)w[u][1];
            h = __builtin_fmaf(f, h, b);
            G[base + (size_t)(tb + u) * 256] = (__bf16)(h * ov[u]);
        }
    }
    hidout[n * 512 + 256 + d] = h;
}

extern "C" void kernel_launch(void* const* d_in, const int* in_sizes, int n_in,
                              void* d_out, int out_size, void* d_ws, size_t ws_size,
                              hipStream_t stream) {
    const float* x      = (const float*)d_in[0];
    const float* hidden = (const float*)d_in[1];
    const float* rs     = (const float*)d_in[2];
    const float* W_in   = (const float*)d_in[3];
    const float* b_in   = (const float*)d_in[4];
    const float* W_mid  = (const float*)d_in[5];
    const float* b_mid  = (const float*)d_in[6];
    const float* W_out  = (const float*)d_in[7];
    const float* b_out  = (const float*)d_in[8];
    float* out = (float*)d_out;

    char* ws = (char*)d_ws;
    const size_t MiB = (size_t)1 << 20;
    __bf16* Wt1 = (__bf16*)(ws + 0);               // 2 MiB
    __bf16* Wt2 = (__bf16*)(ws + 2 * MiB);         // 4 MiB
    __bf16* Wt3 = (__bf16*)(ws + 6 * MiB);         // 1 MiB
    float*  rsp = (float*)(ws + 7 * MiB);          // 32 KiB
    __bf16* v4b = (__bf16*)(ws + 8 * MiB);         // 32 MiB; reused as G
    __bf16* xb  = (__bf16*)(ws + 40 * MiB);        // 32 MiB (dead after gemm1)
    __bf16* g1  = (__bf16*)(ws + 72 * MiB);        // 64 MiB packed (b,f)  (dead after scan1)
    __bf16* FB  = (__bf16*)(ws + 40 * MiB);        // 64 MiB packed (f,b)  overlays xb+g1
    __bf16* O   = (__bf16*)(ws + 104 * MiB);       // 32 MiB o-gate

    float* hidout = out + (size_t)E_ * M_ * 256;

    convx_k<<<16384, 256, 0, stream>>>(x, xb);
    rsprep_k<<<32, 256, 0, stream>>>(rs, rsp);
    transw_k<<<dim3(4, 4, 16), 256, 0, stream>>>(W_in, Wt1, 2, 1);
    transw_k<<<dim3(4, 4, 32), 256, 0, stream>>>(W_mid, Wt2, 4, 1);
    transw_k<<<dim3(4, 4, 8), 256, 0, stream>>>(W_out, Wt3, 1, 0);

    gemm_k<0, 2, 4><<<512, 256, 0, stream>>>(xb, Wt1, b_in, rsp, g1, nullptr, nullptr);
    scan1_k<<<512, 64, 0, stream>>>(g1, hidden, v4b, hidout);
    gemm_k<1, 4, 8><<<512, 256, 0, stream>>>(v4b, Wt2, b_mid, rsp, FB, O, nullptr);
    scan2_k<<<512, 64, 0, stream>>>(FB, O, hidden, v4b, hidout);
    gemm_k<2, 1, 2><<<512, 256, 0, stream>>>(v4b, Wt3, b_out, nullptr, nullptr, nullptr, out);
}

// Round 6
// 208.909 us; speedup vs baseline: 1.2132x; 1.2132x over previous
//
#include <hip/hip_runtime.h>
#include <hip/hip_bf16.h>
#include <stdint.h>
#include <stddef.h>

// E=8, B=16, T=512, DIN=256, D=256; M = B*T = 8192 rows per ensemble member.
// Stage1: u = x @ W_in[m], v=tanh(u0), f=sig(u1)*(1-rs)  -> scan1 -> v4
// Stage2: u = v4 @ W_mid[m], gates f,i,o,z               -> scan2 -> g = h*o
// Stage3: out = g @ W_out + b_out
//
// r6 GEMM: persistent, B in registers (64 VGPR), A staged as FULL 128x256
// tiles (2x64KB LDS dbuf, contiguous-row global_load_lds), ONE barrier +
// ONE counted vmcnt per mt. Fast activations via v_rcp (no IEEE div).

typedef __bf16 bf16x8 __attribute__((ext_vector_type(8)));
typedef __bf16 bf16x4 __attribute__((ext_vector_type(4)));
typedef __bf16 bf16x2 __attribute__((ext_vector_type(2)));
typedef float  f32x4  __attribute__((ext_vector_type(4)));
typedef unsigned int u32x2 __attribute__((ext_vector_type(2)));

#define E_ 8
#define M_ 8192
#define K_ 256

__device__ __forceinline__ float sigm_f(float x) {
    return __builtin_amdgcn_rcpf(1.0f + __expf(-x));
}
__device__ __forceinline__ float tanh_f(float x) {
    return 1.0f - 2.0f * __builtin_amdgcn_rcpf(1.0f + __expf(2.0f * x));
}

__device__ __forceinline__ void g2lds16(const void* g, void* l) {
    __builtin_amdgcn_global_load_lds((const __attribute__((address_space(1))) void*)g,
                                     (__attribute__((address_space(3))) void*)l, 16, 0, 0);
}

// ---------------- convert x to bf16 ----------------
__global__ __launch_bounds__(256) void convx_k(const float* __restrict__ x, __bf16* __restrict__ xb) {
    int i = blockIdx.x * 256 + threadIdx.x;
    float4 v = ((const float4*)x)[i];
    bf16x4 o;
    o[0] = (__bf16)v.x; o[1] = (__bf16)v.y; o[2] = (__bf16)v.z; o[3] = (__bf16)v.w;
    ((bf16x4*)xb)[i] = o;
}

// ---------------- rs -> tile-layout (1-rs) table: rsp[mt*128 + half*64 + r15*4 + i] ----
__global__ __launch_bounds__(256) void rsprep_k(const float* __restrict__ rs, float* __restrict__ rsp) {
    int idx = blockIdx.x * 256 + threadIdx.x;      // 0..8191
    int mt = idx >> 7, rem = idx & 127;
    int half = rem >> 6, r15 = (rem >> 2) & 15, i = rem & 3;
    rsp[idx] = 1.0f - rs[mt * 128 + half * 64 + i * 16 + r15];
}

// ---------------- transpose+convert weights ----------------
// src [GE][K][D] f32 -> dst [E][NG*256][K] bf16; row' = ilv ? d*NG+g : g*256+d
__global__ __launch_bounds__(256) void transw_k(const float* __restrict__ src, __bf16* __restrict__ dst,
                                                int NG, int ilv) {
    int ge = blockIdx.z;
    int g = ge >> 3, e = ge & 7;
    int k0 = blockIdx.x * 64, d0 = blockIdx.y * 64;
    __shared__ float tile[64][65];
    int t = threadIdx.x;
#pragma unroll
    for (int j = 0; j < 16; ++j) {
        int lin = j * 256 + t;
        int r = lin >> 6, c = lin & 63;
        tile[r][c] = src[((size_t)(ge * 256 + k0 + r)) * 256 + d0 + c];
    }
    __syncthreads();
#pragma unroll
    for (int j = 0; j < 16; ++j) {
        int lin = j * 256 + t;
        int r = lin >> 6, c = lin & 63;     // r = d offset, c = k offset
        int d = d0 + r;
        int row = ilv ? (d * NG + g) : (g * 256 + d);
        dst[((size_t)(e * NG * 256 + row)) * K_ + k0 + c] = (__bf16)tile[c][r];
    }
}

// ---------------- persistent GEMM: full-tile staging, 1 barrier/mt ----------------
// A [E][M][256] bf16, Wt [E][NG*256][256] bf16.
// MODE 0: NG=2 interleaved (d*2+g): q = v(d0),f(d0),v(d1),f(d1) -> packed {b,f} slab [E][M][512]
// MODE 1: NG=4 NON-interleaved: 4 gate slabs [g][E][M][256]; g0 sig*(1-rs), g1/g2 sig, g3 tanh
// MODE 2: NG=1 linear+bias -> f32 d_out
template <int MODE, int NG>
__global__ __launch_bounds__(512, 2) void gemm_k(const __bf16* __restrict__ A,
                                                 const __bf16* __restrict__ Wt,
                                                 const float* __restrict__ bias,
                                                 const float* __restrict__ rsp,
                                                 __bf16* __restrict__ gout,
                                                 float* __restrict__ fout) {
    constexpr int NT  = NG * 2;          // n-panels of 128
    constexpr int NMT = 4 * NG;          // m-tiles per block (grid = 256 exactly)
    const int tid = threadIdx.x;
    const int bid = blockIdx.x;          // 256 blocks, bid&7 = e = XCD
    const int e  = bid & 7;
    const int rr = bid >> 3;             // 0..31
    const int nt = rr & (NT - 1);
    const int ms = rr / NT;
    const int mt0 = ms * NMT;
    const int lane = tid & 63, wid = tid >> 6;
    const int wr = wid >> 2, wc = wid & 3;          // 2x4 wave grid: 64 rows x 32 cols
    const int ln15 = lane & 15, ln16 = lane >> 4;

    __shared__ __align__(16) __bf16 As[2][32768];   // 2 x (128 rows x 256 k) = 128 KB

    // ---- B panel into registers: 2 j-tiles x 8 k-steps x bf16x8 = 64 VGPR ----
    bf16x8 Breg[2][8];
    {
        const __bf16* bp = Wt + ((size_t)e * (NG * 256) + nt * 128 + wc * 32 + ln15) * K_ + ln16 * 8;
#pragma unroll
        for (int j = 0; j < 2; ++j)
#pragma unroll
            for (int s = 0; s < 8; ++s)
                Breg[j][s] = *(const bf16x8*)(bp + (size_t)j * 16 * K_ + s * 32);
    }
    // ---- bias preload ----
    f32x4 bias_v[2];
#pragma unroll
    for (int j = 0; j < 2; ++j) {
        int n0 = nt * 128 + wc * 32 + j * 16 + (ln16 << 2);
        if constexpr (MODE == 0) {
#pragma unroll
            for (int q = 0; q < 4; ++q) {
                int n = n0 + q;
                bias_v[j][q] = bias[((n & 1) * E_ + e) * 256 + (n >> 1)];
            }
        } else if constexpr (MODE == 1) {
            bias_v[j] = *(const f32x4*)&bias[((n0 >> 8) * E_ + e) * 256 + (n0 & 255)];
        } else {
            bias_v[j] = *(const f32x4*)&bias[e * 256 + n0];
        }
    }

    // ---- staging: per thread 8 x 16B granules, full contiguous rows ----
    const size_t Ae = ((size_t)e * M_ + (size_t)mt0 * 128) * K_;
    const int srow = tid >> 5;                        // 0..15
    const int scol = (tid & 31) ^ (srow & 7);         // XOR pre-swizzled source granule
    const __bf16* sbase = A + Ae + (size_t)srow * K_ + scol * 8;
    __bf16* const dbase0 = &As[0][tid * 8];
    __bf16* const dbase1 = &As[1][tid * 8];

    auto stage = [&](int t, int buf) {
        const __bf16* s = sbase + (size_t)t * (128 * K_);
        __bf16* d = buf ? dbase1 : dbase0;
#pragma unroll
        for (int q = 0; q < 8; ++q)
            g2lds16(s + q * (16 * K_), d + q * 4096);
    };

    // ---- ds_read fragment bases (lane-constant + immediate offsets) ----
    const int arow = wr * 64 + ln15;
    const int gsw_e = ln16 ^ (lane & 7);
    const int gsw_o = (4 + ln16) ^ (lane & 7);
    const int pe_off = arow * K_ + gsw_e * 8;
    const int po_off = arow * K_ + gsw_o * 8;

    f32x4 acc[4][2] = {};

    auto compute = [&](int buf) {
        const __bf16* pe = &As[buf][pe_off];
        const __bf16* po = &As[buf][po_off];
#pragma unroll
        for (int s = 0; s < 8; ++s) {
            const __bf16* p = (s & 1) ? po : pe;
            bf16x8 af[4];
#pragma unroll
            for (int i = 0; i < 4; ++i)
                af[i] = *(const bf16x8*)(p + i * (16 * K_) + (s >> 1) * 64);
#pragma unroll
            for (int i = 0; i < 4; ++i)
#pragma unroll
                for (int j = 0; j < 2; ++j)
                    acc[i][j] = __builtin_amdgcn_mfma_f32_16x16x32_bf16(Breg[j][s], af[i], acc[i][j], 0, 0, 0);
        }
    };

    // ---- prologue ----
    stage(0, 0);
    asm volatile("s_waitcnt vmcnt(0)" ::: "memory");
    __builtin_amdgcn_s_barrier();
    __builtin_amdgcn_sched_barrier(0);

    int buf = 0;
    for (int t = 0; t < NMT; ++t) {
        if (t + 1 < NMT) stage(t + 1, buf ^ 1);     // 8 loads, overlap with compute
        compute(buf);

        // ---- epilogue for mt = mt0+t (8 stores of 8/16B) ----
        const int mt = mt0 + t;
        const int mlo = mt * 128 + wr * 64 + ln15;
        f32x4 rsv;
        if constexpr (MODE != 2) rsv = *(const f32x4*)&rsp[mt * 128 + wr * 64 + ln15 * 4];
#pragma unroll
        for (int j = 0; j < 2; ++j) {
            const int n0 = nt * 128 + wc * 32 + j * 16 + (ln16 << 2);
#pragma unroll
            for (int i = 0; i < 4; ++i) {
                const int m = mlo + i * 16;
                float u0 = acc[i][j][0] + bias_v[j][0];
                float u1 = acc[i][j][1] + bias_v[j][1];
                float u2 = acc[i][j][2] + bias_v[j][2];
                float u3 = acc[i][j][3] + bias_v[j][3];
                if constexpr (MODE == 2) {
                    f32x4 o; o[0] = u0; o[1] = u1; o[2] = u2; o[3] = u3;
                    *(f32x4*)&fout[((size_t)e * M_ + m) * 256 + n0] = o;
                } else if constexpr (MODE == 0) {
                    // q: v(d0), f(d0), v(d1), f(d1) -> pack {b,f} pairs
                    float v0 = tanh_f(u0), f0 = sigm_f(u1) * rsv[i];
                    float v1 = tanh_f(u2), f1 = sigm_f(u3) * rsv[i];
                    bf16x4 pk;
                    pk[0] = (__bf16)((1.0f - f0) * v0); pk[1] = (__bf16)f0;
                    pk[2] = (__bf16)((1.0f - f1) * v1); pk[3] = (__bf16)f1;
                    *(u32x2*)&gout[((size_t)e * M_ + m) * 512 + n0] = __builtin_bit_cast(u32x2, pk);
                } else {
                    const int g = n0 >> 8, d = n0 & 255;
                    bf16x4 pk;
                    if (g == 0) {
                        pk[0] = (__bf16)(sigm_f(u0) * rsv[i]); pk[1] = (__bf16)(sigm_f(u1) * rsv[i]);
                        pk[2] = (__bf16)(sigm_f(u2) * rsv[i]); pk[3] = (__bf16)(sigm_f(u3) * rsv[i]);
                    } else if (g == 3) {
                        pk[0] = (__bf16)tanh_f(u0); pk[1] = (__bf16)tanh_f(u1);
                        pk[2] = (__bf16)tanh_f(u2); pk[3] = (__bf16)tanh_f(u3);
                    } else {
                        pk[0] = (__bf16)sigm_f(u0); pk[1] = (__bf16)sigm_f(u1);
                        pk[2] = (__bf16)sigm_f(u2); pk[3] = (__bf16)sigm_f(u3);
                    }
                    *(u32x2*)&gout[(((size_t)g * E_ + e) * M_ + m) * 256 + d] = __builtin_bit_cast(u32x2, pk);
                }
                acc[i][j] = f32x4{};
            }
        }
        // loads (oldest) retired; the 8 stores may stay in flight
        asm volatile("s_waitcnt vmcnt(8)" ::: "memory");
        __builtin_amdgcn_s_barrier();
        __builtin_amdgcn_sched_barrier(0);
        buf ^= 1;
    }
}

// ---------------- scan 1: h = f*h + b, packed (b,f) slab [E][M][512] ----
__global__ __launch_bounds__(64) void scan1_k(const __bf16* __restrict__ BF,
                                              const float* __restrict__ hidden,
                                              __bf16* __restrict__ v4b, float* __restrict__ hidout) {
    int gid = blockIdx.x * 64 + threadIdx.x;    // 0..32767
    int n = gid >> 8, d = gid & 255;
    float h = hidden[n * 512 + d];
    const unsigned int* bf = (const unsigned int*)BF;
    size_t base = (size_t)n * 512 * 256 + (size_t)d;   // uint rows of 256
    size_t obase = (size_t)n * 512 * 256 + d;
#pragma unroll 1
    for (int tb = 0; tb < 512; tb += 16) {
        bf16x2 w[16];
#pragma unroll
        for (int u = 0; u < 16; ++u)
            w[u] = __builtin_bit_cast(bf16x2, bf[base + (size_t)(tb + u) * 256]);
#pragma unroll
        for (int u = 0; u < 16; ++u) {
            float b = (float)w[u][0], f = (float)w[u][1];
            h = __builtin_fmaf(f, h, b);
            v4b[obase + (size_t)(tb + u) * 256] = (__bf16)h;
        }
    }
    hidout[n * 512 + d] = h;
}

// ---------------- scan 2: h = f*h + (1-f)*(i*z); out = h*o ----
__global__ __launch_bounds__(64) void scan2_k(const __bf16* __restrict__ Fg, const __bf16* __restrict__ Ig,
                                              const __bf16* __restrict__ Og, const __bf16* __restrict__ Zg,
                                              const float* __restrict__ hidden,
                                              __bf16* __restrict__ G, float* __restrict__ hidout) {
    int gid = blockIdx.x * 64 + threadIdx.x;
    int n = gid >> 8, d = gid & 255;
    float h = hidden[n * 512 + 256 + d];
    size_t base = (size_t)n * 512 * 256 + d;
#pragma unroll 1
    for (int tb = 0; tb < 512; tb += 16) {
        float fv[16], bv[16], ov[16];
#pragma unroll
        for (int u = 0; u < 16; ++u) {
            size_t idx = base + (size_t)(tb + u) * 256;
            float f = (float)Fg[idx], iv = (float)Ig[idx], o = (float)Og[idx], z = (float)Zg[idx];
            fv[u] = f; bv[u] = (1.0f - f) * (iv * z); ov[u] = o;
        }
#pragma unroll
        for (int u = 0; u < 16; ++u) {
            h = __builtin_fmaf(fv[u], h, bv[u]);
            size_t idx = base + (size_t)(tb + u) * 256;
            G[idx] = (__bf16)(h * ov[u]);
        }
    }
    hidout[n * 512 + 256 + d] = h;
}

extern "C" void kernel_launch(void* const* d_in, const int* in_sizes, int n_in,
                              void* d_out, int out_size, void* d_ws, size_t ws_size,
                              hipStream_t stream) {
    const float* x      = (const float*)d_in[0];
    const float* hidden = (const float*)d_in[1];
    const float* rs     = (const float*)d_in[2];
    const float* W_in   = (const float*)d_in[3];
    const float* b_in   = (const float*)d_in[4];
    const float* W_mid  = (const float*)d_in[5];
    const float* b_mid  = (const float*)d_in[6];
    const float* W_out  = (const float*)d_in[7];
    const float* b_out  = (const float*)d_in[8];
    float* out = (float*)d_out;

    char* ws = (char*)d_ws;
    const size_t MiB = (size_t)1 << 20;
    __bf16* Wt1 = (__bf16*)(ws + 0);               // 2 MiB  (interleaved d*2+g)
    __bf16* Wt2 = (__bf16*)(ws + 2 * MiB);         // 4 MiB  (plain g*256+d)
    __bf16* Wt3 = (__bf16*)(ws + 6 * MiB);         // 1 MiB
    float*  rsp = (float*)(ws + 7 * MiB);          // 32 KiB
    __bf16* v4b = (__bf16*)(ws + 8 * MiB);         // 32 MiB; reused as G
    __bf16* xb  = (__bf16*)(ws + 40 * MiB);        // 32 MiB (dead after gemm1)
    __bf16* g1  = (__bf16*)(ws + 72 * MiB);        // 64 MiB packed (b,f) (dead after scan1)
    __bf16* g2  = (__bf16*)(ws + 40 * MiB);        // 128 MiB 4 slabs, overlays xb+g1
    const size_t S1 = (size_t)E_ * M_ * 256;

    float* hidout = out + (size_t)E_ * M_ * 256;

    convx_k<<<16384, 256, 0, stream>>>(x, xb);
    rsprep_k<<<32, 256, 0, stream>>>(rs, rsp);
    transw_k<<<dim3(4, 4, 16), 256, 0, stream>>>(W_in, Wt1, 2, 1);
    transw_k<<<dim3(4, 4, 32), 256, 0, stream>>>(W_mid, Wt2, 4, 0);
    transw_k<<<dim3(4, 4, 8), 256, 0, stream>>>(W_out, Wt3, 1, 0);

    gemm_k<0, 2><<<256, 512, 0, stream>>>(xb, Wt1, b_in, rsp, g1, nullptr);
    scan1_k<<<512, 64, 0, stream>>>(g1, hidden, v4b, hidout);
    gemm_k<1, 4><<<256, 512, 0, stream>>>(v4b, Wt2, b_mid, rsp, g2, nullptr);
    scan2_k<<<512, 64, 0, stream>>>(g2, g2 + S1, g2 + 2 * S1, g2 + 3 * S1, hidden, v4b, hidout);
    gemm_k<2, 1><<<256, 512, 0, stream>>>(v4b, Wt3, b_out, nullptr, nullptr, out);
}